// Round 2
// baseline (5674.128 us; speedup 1.0000x reference)
//
#include <hip/hip_runtime.h>
#include <math.h>

#define Q 256

typedef unsigned short u16;
typedef unsigned int u32;

__device__ __forceinline__ float bf2f(u32 u){
  union { float f; u32 i; } v; v.i = u << 16; return v.f;
}
__device__ __forceinline__ u16 f2bf(float f){
  union { float f; u32 i; } v; v.f = f;
  u32 r = (v.i + 0x7FFFu + ((v.i >> 16) & 1u)) >> 16;
  return (u16)r;
}
__device__ __forceinline__ void unpack8(uint4 v, float* o){
  o[0]=bf2f(v.x & 0xffffu); o[1]=bf2f(v.x >> 16);
  o[2]=bf2f(v.y & 0xffffu); o[3]=bf2f(v.y >> 16);
  o[4]=bf2f(v.z & 0xffffu); o[5]=bf2f(v.z >> 16);
  o[6]=bf2f(v.w & 0xffffu); o[7]=bf2f(v.w >> 16);
}
__device__ __forceinline__ float softplusf(float x){
  return x > 20.f ? x : log1pf(expf(x));
}
__device__ __forceinline__ float siluf(float x){
  return x / (1.f + expf(-x));
}

// Shared 64x64-tile fp32 GEMM core: C_tile = A[64,K] @ B[64,K]^T, acc in regs.
#define GEMM_CORE(A_, B_, K_) \
  __shared__ float As[16][64]; \
  __shared__ float Bs[16][64]; \
  const int tid = threadIdx.x; \
  const int m0 = blockIdx.y * 64, n0 = blockIdx.x * 64; \
  const int tx = tid & 15, ty = tid >> 4; \
  const int lr = tid >> 2, lk = (tid & 3) << 2; \
  float acc[4][4] = {}; \
  { const float* Ap = (A_) + (size_t)(m0 + lr) * (K_) + lk; \
    const float* Bp = (B_) + (size_t)(n0 + lr) * (K_) + lk; \
    for (int k0 = 0; k0 < (K_); k0 += 16) { \
      float4 av = *(const float4*)(Ap + k0); \
      float4 bv = *(const float4*)(Bp + k0); \
      __syncthreads(); \
      As[lk+0][lr]=av.x; As[lk+1][lr]=av.y; As[lk+2][lr]=av.z; As[lk+3][lr]=av.w; \
      Bs[lk+0][lr]=bv.x; Bs[lk+1][lr]=bv.y; Bs[lk+2][lr]=bv.z; Bs[lk+3][lr]=bv.w; \
      __syncthreads(); \
      _Pragma("unroll") \
      for (int k = 0; k < 16; k++) { \
        float a_[4], b_[4]; \
        _Pragma("unroll") for (int i = 0; i < 4; i++) a_[i] = As[k][ty*4+i]; \
        _Pragma("unroll") for (int j = 0; j < 4; j++) b_[j] = Bs[k][tx*4+j]; \
        _Pragma("unroll") for (int i = 0; i < 4; i++) \
          _Pragma("unroll") for (int j = 0; j < 4; j++) \
            acc[i][j] = fmaf(a_[i], b_[j], acc[i][j]); \
      } \
    } }

// in-proj: xr = x @ w_in.T ; split into inp (cols<4096) and res, both bf16.
__global__ __launch_bounds__(256) void gemm_in(const float* __restrict__ A,
    const float* __restrict__ B, u16* __restrict__ inp, u16* __restrict__ resb)
{
  GEMM_CORE(A, B, 2048)
  #pragma unroll
  for (int i = 0; i < 4; i++) {
    const int m = m0 + ty*4 + i;
    #pragma unroll
    for (int j = 0; j < 4; j++) {
      const int n = n0 + tx*4 + j;
      const u16 v = f2bf(acc[i][j]);
      if (n < 4096) inp[(size_t)m*4096 + n] = v;
      else          resb[(size_t)m*4096 + (n - 4096)] = v;
    }
  }
}

// param-proj: params = x @ w_param.T, scattered into dtb (fp32), Bb, Cb (bf16).
__global__ __launch_bounds__(256) void gemm_par(const float* __restrict__ A,
    const float* __restrict__ B, float* __restrict__ dtb,
    u16* __restrict__ Bb, u16* __restrict__ Cb)
{
  GEMM_CORE(A, B, 2048)
  #pragma unroll
  for (int i = 0; i < 4; i++) {
    const int m = m0 + ty*4 + i;
    #pragma unroll
    for (int j = 0; j < 4; j++) {
      const int n = n0 + tx*4 + j;
      const int h = n / 129, r = n - h*129;
      const float v = acc[i][j];
      if (r == 0)       dtb[(size_t)m*64 + h] = v;
      else if (r < 65)  Bb[((size_t)m*64 + h)*64 + (r-1)]  = f2bf(v);
      else              Cb[((size_t)m*64 + h)*64 + (r-65)] = f2bf(v);
    }
  }
}

// out-proj: out = y @ w_out.T (fp32).
__global__ __launch_bounds__(256) void gemm_out(const float* __restrict__ A,
    const float* __restrict__ B, float* __restrict__ C)
{
  GEMM_CORE(A, B, 4096)
  #pragma unroll
  for (int i = 0; i < 4; i++)
    #pragma unroll
    for (int j = 0; j < 4; j++)
      C[(size_t)(m0 + ty*4 + i)*2048 + n0 + tx*4 + j] = acc[i][j];
}

// Per chunk g: within-chunk cumsum of log(a), A_chunk, and chunk state
// states[g][s][d] = sum_j exp(cs_last - cs_j) B[j][s] X[j][d].
__global__ __launch_bounds__(256) void ssd_phaseA(const float* __restrict__ dtb,
    const u16* __restrict__ Bb, const u16* __restrict__ inp,
    float* __restrict__ cs_g, float* __restrict__ achunk, float* __restrict__ states)
{
  const int g = blockIdx.x, tid = threadIdx.x;
  const int p = g * Q + tid;
  __shared__ float sc[Q];
  sc[tid] = -softplusf(dtb[p]);
  __syncthreads();
  for (int off = 1; off < Q; off <<= 1) {
    float v = (tid >= off) ? sc[tid - off] : 0.f;
    __syncthreads();
    if (tid >= off) sc[tid] += v;
    __syncthreads();
  }
  const float cs = sc[tid];
  cs_g[p] = cs;
  const float cl = sc[Q-1];
  if (tid == 0) achunk[g] = expf(cl);

  __shared__ float sB[64][64];
  __shared__ float sX[64][64];
  const int tx = tid & 15, ty = tid >> 4;
  const int jr = tid >> 2, c0 = (tid & 3) << 4;
  float acc[4][4] = {};
  for (int jt = 0; jt < 4; jt++) {
    const int pj = g * Q + jt*64 + jr;
    const float wj = expf(cl - sc[jt*64 + jr]);
    const uint4 b0 = *(const uint4*)&Bb[(size_t)pj*64 + c0];
    const uint4 b1 = *(const uint4*)&Bb[(size_t)pj*64 + c0 + 8];
    const uint4 x0 = *(const uint4*)&inp[(size_t)pj*64 + c0];
    const uint4 x1 = *(const uint4*)&inp[(size_t)pj*64 + c0 + 8];
    float bb[16], xx[16];
    unpack8(b0, bb); unpack8(b1, bb+8);
    unpack8(x0, xx); unpack8(x1, xx+8);
    __syncthreads();
    #pragma unroll
    for (int q = 0; q < 16; q++) { sB[jr][c0+q] = wj*bb[q]; sX[jr][c0+q] = xx[q]; }
    __syncthreads();
    #pragma unroll
    for (int k = 0; k < 64; k++) {
      float b_[4], x_[4];
      #pragma unroll
      for (int i = 0; i < 4; i++) b_[i] = sB[k][ty*4+i];
      #pragma unroll
      for (int j = 0; j < 4; j++) x_[j] = sX[k][tx*4+j];
      #pragma unroll
      for (int i = 0; i < 4; i++)
        #pragma unroll
        for (int j = 0; j < 4; j++)
          acc[i][j] = fmaf(b_[i], x_[j], acc[i][j]);
    }
  }
  #pragma unroll
  for (int i = 0; i < 4; i++)
    #pragma unroll
    for (int j = 0; j < 4; j++)
      states[(size_t)g * 4096 + (ty*4+i)*64 + tx*4 + j] = acc[i][j];
}

// Sequential scan over the 16 chunks of each pseudo-batch; in place:
// states[g] is replaced by the state BEFORE chunk g.
__global__ __launch_bounds__(256) void ssd_scan(float* __restrict__ states,
    const float* __restrict__ achunk)
{
  const int n = blockIdx.x, tid = threadIdx.x;
  float S[16];
  #pragma unroll
  for (int k = 0; k < 16; k++) S[k] = 0.f;
  for (int c = 0; c < 16; c++) {
    const int g = n*16 + c;
    const float A = achunk[g];
    #pragma unroll
    for (int k = 0; k < 16; k++) {
      const size_t e = (size_t)g * 4096 + tid + k*256;
      const float st = states[e];
      states[e] = S[k];
      S[k] = fmaf(A, S[k], st);
    }
  }
}

// y_diag: block = (i-tile, chunk). Triangular over j-tiles.
__global__ __launch_bounds__(256) void ssd_diag(const u16* __restrict__ Bb,
    const u16* __restrict__ Cb, const u16* __restrict__ inp,
    const float* __restrict__ cs_g, float* __restrict__ y)
{
  const int g = blockIdx.y, it = blockIdx.x, tid = threadIdx.x;
  const int p_base = g * Q;
  __shared__ float Cs[64][64];
  __shared__ float BX[64][64];
  __shared__ float Ss[64][64];
  __shared__ float csi[64], csj[64];
  const int r = tid >> 2, c0 = (tid & 3) << 4;
  {
    const int pi = p_base + it*64 + r;
    const uint4 v0 = *(const uint4*)&Cb[(size_t)pi*64 + c0];
    const uint4 v1 = *(const uint4*)&Cb[(size_t)pi*64 + c0 + 8];
    float cc[16]; unpack8(v0, cc); unpack8(v1, cc+8);
    #pragma unroll
    for (int q = 0; q < 16; q++) Cs[r][c0+q] = cc[q];
    if (tid < 64) csi[tid] = cs_g[p_base + it*64 + tid];
  }
  const int tx = tid & 15, ty = tid >> 4;
  float acc[4][4] = {};
  for (int jt = 0; jt <= it; jt++) {
    __syncthreads();
    {
      const int pj = p_base + jt*64 + r;
      const uint4 v0 = *(const uint4*)&Bb[(size_t)pj*64 + c0];
      const uint4 v1 = *(const uint4*)&Bb[(size_t)pj*64 + c0 + 8];
      float bb[16]; unpack8(v0, bb); unpack8(v1, bb+8);
      #pragma unroll
      for (int q = 0; q < 16; q++) BX[c0+q][r] = bb[q];
      if (tid < 64) csj[tid] = cs_g[p_base + jt*64 + tid];
    }
    __syncthreads();
    #pragma unroll
    for (int rr = 0; rr < 16; rr++) {
      const int idx = rr*256 + tid;
      const int i = idx >> 6, jj = idx & 63;
      float s = 0.f;
      if (jt*64 + jj <= it*64 + i) {
        float d = 0.f;
        #pragma unroll
        for (int k = 0; k < 64; k++) d = fmaf(Cs[i][k], BX[k][jj], d);
        s = d * expf(csi[i] - csj[jj]);
      }
      Ss[i][jj] = s;
    }
    __syncthreads();
    {
      const int pj = p_base + jt*64 + r;
      const uint4 v0 = *(const uint4*)&inp[(size_t)pj*64 + c0];
      const uint4 v1 = *(const uint4*)&inp[(size_t)pj*64 + c0 + 8];
      float xx[16]; unpack8(v0, xx); unpack8(v1, xx+8);
      #pragma unroll
      for (int q = 0; q < 16; q++) BX[r][c0+q] = xx[q];
    }
    __syncthreads();
    #pragma unroll
    for (int k = 0; k < 64; k++) {
      float sv[4], xv[4];
      #pragma unroll
      for (int i = 0; i < 4; i++) sv[i] = Ss[ty*4+i][k];
      #pragma unroll
      for (int j = 0; j < 4; j++) xv[j] = BX[k][tx*4+j];
      #pragma unroll
      for (int i = 0; i < 4; i++)
        #pragma unroll
        for (int j = 0; j < 4; j++)
          acc[i][j] = fmaf(sv[i], xv[j], acc[i][j]);
    }
  }
  #pragma unroll
  for (int i = 0; i < 4; i++) {
    const int pi = p_base + it*64 + ty*4 + i;
    #pragma unroll
    for (int j = 0; j < 4; j++)
      y[(size_t)pi * 64 + tx*4 + j] = acc[i][j];
  }
}

// y_inter + add y_diag + SiLU gate (in place into y).
__global__ __launch_bounds__(256) void ssd_inter(const u16* __restrict__ Cb,
    const float* __restrict__ cs_g, const float* __restrict__ sprev,
    const u16* __restrict__ resb, float* __restrict__ y)
{
  const int g = blockIdx.x, tid = threadIdx.x;
  const int p = g * Q + tid;
  __shared__ float Sp[64][64];
  #pragma unroll
  for (int k = 0; k < 16; k++)
    ((float*)Sp)[tid + k*256] = sprev[(size_t)g*4096 + tid + k*256];
  __syncthreads();
  const float ei = expf(cs_g[p]);
  float yacc[64];
  #pragma unroll
  for (int d = 0; d < 64; d++) yacc[d] = 0.f;
  const u16* crow = &Cb[(size_t)p * 64];
  for (int s = 0; s < 64; s++) {
    const float c = bf2f((u32)crow[s]) * ei;
    #pragma unroll
    for (int d = 0; d < 64; d++) yacc[d] = fmaf(c, Sp[s][d], yacc[d]);
  }
  #pragma unroll
  for (int d0 = 0; d0 < 64; d0 += 8) {
    const uint4 rv = *(const uint4*)&resb[(size_t)p*64 + d0];
    float rr[8]; unpack8(rv, rr);
    float4 y0 = *(float4*)&y[(size_t)p*64 + d0];
    float4 y1 = *(float4*)&y[(size_t)p*64 + d0 + 4];
    float o[8];
    o[0]=y0.x+yacc[d0+0]; o[1]=y0.y+yacc[d0+1]; o[2]=y0.z+yacc[d0+2]; o[3]=y0.w+yacc[d0+3];
    o[4]=y1.x+yacc[d0+4]; o[5]=y1.y+yacc[d0+5]; o[6]=y1.z+yacc[d0+6]; o[7]=y1.w+yacc[d0+7];
    #pragma unroll
    for (int q = 0; q < 8; q++) o[q] *= siluf(rr[q]);
    y0.x=o[0]; y0.y=o[1]; y0.z=o[2]; y0.w=o[3];
    y1.x=o[4]; y1.y=o[5]; y1.z=o[6]; y1.w=o[7];
    *(float4*)&y[(size_t)p*64 + d0] = y0;
    *(float4*)&y[(size_t)p*64 + d0 + 4] = y1;
  }
}

extern "C" void kernel_launch(void* const* d_in, const int* in_sizes, int n_in,
                              void* d_out, int out_size, void* d_ws, size_t ws_size,
                              hipStream_t stream)
{
  const float* x       = (const float*)d_in[0];
  const float* w_in    = (const float*)d_in[1];
  const float* w_param = (const float*)d_in[2];
  const float* w_out   = (const float*)d_in[3];
  float* out = (float*)d_out;
  char* ws = (char*)d_ws;

  // total ws use: 0xD300000 = 221,249,536 bytes (~211 MiB)
  u16*   inp    = (u16*)  (ws);                  // 4096*4096 bf16 = 32 MiB
  u16*   resb   = (u16*)  (ws + 0x2000000ull);   // 32 MiB
  u16*   Bb     = (u16*)  (ws + 0x4000000ull);   // 262144*64 bf16 = 32 MiB
  u16*   Cb     = (u16*)  (ws + 0x6000000ull);   // 32 MiB
  float* dtb    = (float*)(ws + 0x8000000ull);   // 262144 f32 = 1 MiB
  float* cs     = (float*)(ws + 0x8100000ull);   // 1 MiB
  float* achunk = (float*)(ws + 0x8200000ull);   // 4 KiB
  float* y      = (float*)(ws + 0x8300000ull);   // 4096*4096 f32 = 64 MiB
  float* states = (float*)(ws + 0xC300000ull);   // 1024*4096 f32 = 16 MiB

  gemm_in <<<dim3(128, 64), 256, 0, stream>>>(x, w_in, inp, resb);
  gemm_par<<<dim3(129, 64), 256, 0, stream>>>(x, w_param, dtb, Bb, Cb);
  ssd_phaseA<<<1024, 256, 0, stream>>>(dtb, Bb, inp, cs, achunk, states);
  ssd_scan<<<64, 256, 0, stream>>>(states, achunk);
  ssd_diag<<<dim3(4, 1024), 256, 0, stream>>>(Bb, Cb, inp, cs, y);
  ssd_inter<<<1024, 256, 0, stream>>>(Cb, cs, states, resb, y);
  gemm_out<<<dim3(32, 64), 256, 0, stream>>>(y, w_out, out);
}

// Round 3
// 1143.933 us; speedup vs baseline: 4.9602x; 4.9602x over previous
//
#include <hip/hip_runtime.h>
#include <math.h>

#define Q 256

typedef unsigned short u16;
typedef unsigned int u32;
typedef __attribute__((ext_vector_type(8))) short short8;
typedef __attribute__((ext_vector_type(4))) float f32x4;

__device__ __forceinline__ float bf2f(u32 u){
  union { float f; u32 i; } v; v.i = u << 16; return v.f;
}
__device__ __forceinline__ u16 f2bf(float f){
  union { float f; u32 i; } v; v.f = f;
  u32 r = (v.i + 0x7FFFu + ((v.i >> 16) & 1u)) >> 16;
  return (u16)r;
}
__device__ __forceinline__ void unpack8(uint4 v, float* o){
  o[0]=bf2f(v.x & 0xffffu); o[1]=bf2f(v.x >> 16);
  o[2]=bf2f(v.y & 0xffffu); o[3]=bf2f(v.y >> 16);
  o[4]=bf2f(v.z & 0xffffu); o[5]=bf2f(v.z >> 16);
  o[6]=bf2f(v.w & 0xffffu); o[7]=bf2f(v.w >> 16);
}
__device__ __forceinline__ float softplusf(float x){
  return x > 20.f ? x : log1pf(expf(x));
}
__device__ __forceinline__ float siluf(float x){
  return x / (1.f + expf(-x));
}

__device__ __forceinline__ void gload_lds16(const void* g, const void* l){
  __builtin_amdgcn_global_load_lds(
    (const __attribute__((address_space(1))) void*)(uintptr_t)g,
    (__attribute__((address_space(3))) void*)(u32)(uintptr_t)l,
    16, 0, 0);
}

__global__ __launch_bounds__(256) void cast_bf16(const float* __restrict__ in,
    u16* __restrict__ out)
{
  const size_t i = ((size_t)blockIdx.x * 256 + threadIdx.x) * 4;
  const float4 v = *(const float4*)(in + i);
  ushort4 o;
  o.x = f2bf(v.x); o.y = f2bf(v.y); o.z = f2bf(v.z); o.w = f2bf(v.w);
  *(ushort4*)(out + i) = o;
}

// MFMA GEMM core: C[128x128 tile] = A[M,K]bf16 @ B[N,K]bf16^T, fp32 acc.
// 4 waves (2x2), each wave 64x64 out = 4x4 frags of 16x16, BK=64.
// LDS linear [128][64]; swizzle applied on global source + ds_read (rule #21).
#define MFMA_GEMM_CORE(Abf_, Bbf_, K_) \
  __shared__ short As[128*64]; \
  __shared__ short Bs[128*64]; \
  const int tid = threadIdx.x; \
  const int w = tid >> 6, l = tid & 63; \
  const int m0 = blockIdx.y * 128, n0 = blockIdx.x * 128; \
  const int wr = (w >> 1) * 64, wc = (w & 1) * 64; \
  const int sub = l >> 3; \
  const int scol = ((l & 7) ^ sub) * 8; \
  const int lr16 = l & 15; \
  const int koff = (l >> 4) << 4; \
  const int swz = (l & 7) << 4; \
  f32x4 acc[4][4]; \
  { f32x4 z = {0.f, 0.f, 0.f, 0.f}; \
    _Pragma("unroll") for (int m_ = 0; m_ < 4; m_++) \
    _Pragma("unroll") for (int n_ = 0; n_ < 4; n_++) acc[m_][n_] = z; } \
  const u16* Agp = (Abf_) + (size_t)m0 * (K_); \
  const u16* Bgp = (Bbf_) + (size_t)n0 * (K_); \
  for (int kt = 0; kt < (K_); kt += 64) { \
    __syncthreads(); \
    _Pragma("unroll") for (int i_ = 0; i_ < 4; i_++) { \
      const int rbase = i_*32 + w*8; \
      gload_lds16(Agp + (size_t)(rbase + sub)*(K_) + kt + scol, As + rbase*64); \
      gload_lds16(Bgp + (size_t)(rbase + sub)*(K_) + kt + scol, Bs + rbase*64); \
    } \
    __syncthreads(); \
    short8 af[2][4], bf[2][4]; \
    _Pragma("unroll") for (int kk = 0; kk < 2; kk++) { \
      _Pragma("unroll") for (int m_ = 0; m_ < 4; m_++) \
        af[kk][m_] = *(const short8*)((const char*)As + (wr + m_*16 + lr16)*128 + ((kk*64 + koff) ^ swz)); \
      _Pragma("unroll") for (int n_ = 0; n_ < 4; n_++) \
        bf[kk][n_] = *(const short8*)((const char*)Bs + (wc + n_*16 + lr16)*128 + ((kk*64 + koff) ^ swz)); \
    } \
    _Pragma("unroll") for (int m_ = 0; m_ < 4; m_++) \
    _Pragma("unroll") for (int n_ = 0; n_ < 4; n_++) \
    _Pragma("unroll") for (int kk = 0; kk < 2; kk++) \
      acc[m_][n_] = __builtin_amdgcn_mfma_f32_16x16x32_bf16(af[kk][m_], bf[kk][n_], acc[m_][n_], 0, 0, 0); \
  } \
  const int orow0 = m0 + wr + ((l >> 4) << 2); \
  const int ocol0 = n0 + wc + (l & 15);

// in-proj: inp = cols<4096, resb = cols>=4096, both bf16.
__global__ __launch_bounds__(256) void gemm_in(const u16* __restrict__ A,
    const u16* __restrict__ B, u16* __restrict__ inp, u16* __restrict__ resb)
{
  MFMA_GEMM_CORE(A, B, 2048)
  #pragma unroll
  for (int m_ = 0; m_ < 4; m_++)
    #pragma unroll
    for (int n_ = 0; n_ < 4; n_++) {
      const int col = ocol0 + n_*16;
      #pragma unroll
      for (int j = 0; j < 4; j++) {
        const int row = orow0 + m_*16 + j;
        const u16 v = f2bf(acc[m_][n_][j]);
        if (col < 4096) inp[(size_t)row*4096 + col] = v;
        else            resb[(size_t)row*4096 + (col - 4096)] = v;
      }
    }
}

// param-proj: scatter n -> (h = n/129, r = n%129): dt fp32 / B bf16 / C bf16.
__global__ __launch_bounds__(256) void gemm_par(const u16* __restrict__ A,
    const u16* __restrict__ B, float* __restrict__ dtb,
    u16* __restrict__ Bb, u16* __restrict__ Cb)
{
  MFMA_GEMM_CORE(A, B, 2048)
  #pragma unroll
  for (int m_ = 0; m_ < 4; m_++)
    #pragma unroll
    for (int n_ = 0; n_ < 4; n_++) {
      const int col = ocol0 + n_*16;
      if (col < 8256) {
        const int h = col / 129, rr = col - h*129;
        #pragma unroll
        for (int j = 0; j < 4; j++) {
          const int row = orow0 + m_*16 + j;
          const float v = acc[m_][n_][j];
          if (rr == 0)      dtb[(size_t)row*64 + h] = v;
          else if (rr < 65) Bb[((size_t)row*64 + h)*64 + (rr-1)]  = f2bf(v);
          else              Cb[((size_t)row*64 + h)*64 + (rr-65)] = f2bf(v);
        }
      }
    }
}

// out-proj: fp32 out.
__global__ __launch_bounds__(256) void gemm_out(const u16* __restrict__ A,
    const u16* __restrict__ B, float* __restrict__ C)
{
  MFMA_GEMM_CORE(A, B, 4096)
  #pragma unroll
  for (int m_ = 0; m_ < 4; m_++)
    #pragma unroll
    for (int n_ = 0; n_ < 4; n_++) {
      const int col = ocol0 + n_*16;
      #pragma unroll
      for (int j = 0; j < 4; j++)
        C[(size_t)(orow0 + m_*16 + j)*2048 + col] = acc[m_][n_][j];
    }
}

// Per chunk g: cumsum of log(a), A_chunk, chunk state
// states[g][s][d] = sum_j exp(cs_last - cs_j) B[j][s] X[j][d].
__global__ __launch_bounds__(256) void ssd_phaseA(const float* __restrict__ dtb,
    const u16* __restrict__ Bb, const u16* __restrict__ inp,
    float* __restrict__ cs_g, float* __restrict__ achunk, float* __restrict__ states)
{
  const int g = blockIdx.x, tid = threadIdx.x;
  const int p = g * Q + tid;
  __shared__ float sc[Q];
  sc[tid] = -softplusf(dtb[p]);
  __syncthreads();
  for (int off = 1; off < Q; off <<= 1) {
    float v = (tid >= off) ? sc[tid - off] : 0.f;
    __syncthreads();
    if (tid >= off) sc[tid] += v;
    __syncthreads();
  }
  const float cs = sc[tid];
  cs_g[p] = cs;
  const float cl = sc[Q-1];
  if (tid == 0) achunk[g] = expf(cl);

  __shared__ float sB[64][64];
  __shared__ float sX[64][64];
  const int tx = tid & 15, ty = tid >> 4;
  const int jr = tid >> 2, c0 = (tid & 3) << 4;
  float acc[4][4] = {};
  for (int jt = 0; jt < 4; jt++) {
    const int pj = g * Q + jt*64 + jr;
    const float wj = expf(cl - sc[jt*64 + jr]);
    const uint4 b0 = *(const uint4*)&Bb[(size_t)pj*64 + c0];
    const uint4 b1 = *(const uint4*)&Bb[(size_t)pj*64 + c0 + 8];
    const uint4 x0 = *(const uint4*)&inp[(size_t)pj*64 + c0];
    const uint4 x1 = *(const uint4*)&inp[(size_t)pj*64 + c0 + 8];
    float bb[16], xx[16];
    unpack8(b0, bb); unpack8(b1, bb+8);
    unpack8(x0, xx); unpack8(x1, xx+8);
    __syncthreads();
    #pragma unroll
    for (int q = 0; q < 16; q++) { sB[jr][c0+q] = wj*bb[q]; sX[jr][c0+q] = xx[q]; }
    __syncthreads();
    #pragma unroll
    for (int k = 0; k < 64; k++) {
      float b_[4], x_[4];
      #pragma unroll
      for (int i = 0; i < 4; i++) b_[i] = sB[k][ty*4+i];
      #pragma unroll
      for (int j = 0; j < 4; j++) x_[j] = sX[k][tx*4+j];
      #pragma unroll
      for (int i = 0; i < 4; i++)
        #pragma unroll
        for (int j = 0; j < 4; j++)
          acc[i][j] = fmaf(b_[i], x_[j], acc[i][j]);
    }
  }
  #pragma unroll
  for (int i = 0; i < 4; i++)
    #pragma unroll
    for (int j = 0; j < 4; j++)
      states[(size_t)g * 4096 + (ty*4+i)*64 + tx*4 + j] = acc[i][j];
}

// Sequential scan; in place: states[g] becomes the state BEFORE chunk g.
__global__ __launch_bounds__(256) void ssd_scan(float* __restrict__ states,
    const float* __restrict__ achunk)
{
  const int n = blockIdx.x, tid = threadIdx.x;
  float S[16];
  #pragma unroll
  for (int k = 0; k < 16; k++) S[k] = 0.f;
  for (int c = 0; c < 16; c++) {
    const int g = n*16 + c;
    const float A = achunk[g];
    #pragma unroll
    for (int k = 0; k < 16; k++) {
      const size_t e = (size_t)g * 4096 + tid + k*256;
      const float st = states[e];
      states[e] = S[k];
      S[k] = fmaf(A, S[k], st);
    }
  }
}

// y_diag + y_inter + SiLU gate fused; writes bf16 yb.
__global__ __launch_bounds__(256) void ssd_diag(const u16* __restrict__ Bb,
    const u16* __restrict__ Cb, const u16* __restrict__ inp,
    const float* __restrict__ cs_g, const float* __restrict__ states,
    const u16* __restrict__ resb, u16* __restrict__ yb)
{
  const int g = blockIdx.y, it = blockIdx.x, tid = threadIdx.x;
  const int p_base = g * Q;
  __shared__ float Cs[64][64];
  __shared__ float BX[64][64];
  __shared__ float Ss[64][64];
  __shared__ float csi[64], csj[64];
  const int r = tid >> 2, c0 = (tid & 3) << 4;
  {
    const int pi = p_base + it*64 + r;
    const uint4 v0 = *(const uint4*)&Cb[(size_t)pi*64 + c0];
    const uint4 v1 = *(const uint4*)&Cb[(size_t)pi*64 + c0 + 8];
    float cc[16]; unpack8(v0, cc); unpack8(v1, cc+8);
    #pragma unroll
    for (int q = 0; q < 16; q++) Cs[r][c0+q] = cc[q];
    if (tid < 64) csi[tid] = cs_g[p_base + it*64 + tid];
  }
  const int tx = tid & 15, ty = tid >> 4;
  float acc[4][4] = {};
  for (int jt = 0; jt <= it; jt++) {
    __syncthreads();
    {
      const int pj = p_base + jt*64 + r;
      const uint4 v0 = *(const uint4*)&Bb[(size_t)pj*64 + c0];
      const uint4 v1 = *(const uint4*)&Bb[(size_t)pj*64 + c0 + 8];
      float bb[16]; unpack8(v0, bb); unpack8(v1, bb+8);
      #pragma unroll
      for (int q = 0; q < 16; q++) BX[c0+q][r] = bb[q];
      if (tid < 64) csj[tid] = cs_g[p_base + jt*64 + tid];
    }
    __syncthreads();
    #pragma unroll
    for (int rr = 0; rr < 16; rr++) {
      const int idx = rr*256 + tid;
      const int i = idx >> 6, jj = idx & 63;
      float s = 0.f;
      if (jt*64 + jj <= it*64 + i) {
        float d = 0.f;
        #pragma unroll
        for (int k = 0; k < 64; k++) d = fmaf(Cs[i][k], BX[k][jj], d);
        s = d * expf(csi[i] - csj[jj]);
      }
      Ss[i][jj] = s;
    }
    __syncthreads();
    {
      const int pj = p_base + jt*64 + r;
      const uint4 v0 = *(const uint4*)&inp[(size_t)pj*64 + c0];
      const uint4 v1 = *(const uint4*)&inp[(size_t)pj*64 + c0 + 8];
      float xx[16]; unpack8(v0, xx); unpack8(v1, xx+8);
      #pragma unroll
      for (int q = 0; q < 16; q++) BX[r][c0+q] = xx[q];
    }
    __syncthreads();
    #pragma unroll
    for (int k = 0; k < 64; k++) {
      float sv[4], xv[4];
      #pragma unroll
      for (int i = 0; i < 4; i++) sv[i] = Ss[ty*4+i][k];
      #pragma unroll
      for (int j = 0; j < 4; j++) xv[j] = BX[k][tx*4+j];
      #pragma unroll
      for (int i = 0; i < 4; i++)
        #pragma unroll
        for (int j = 0; j < 4; j++)
          acc[i][j] = fmaf(sv[i], xv[j], acc[i][j]);
    }
  }
  // y_inter: acc += (C * exp(cs)) @ S_prev
  __syncthreads();
  #pragma unroll
  for (int q = 0; q < 16; q += 4) {
    const float4 v = *(const float4*)&states[(size_t)g*4096 + r*64 + c0 + q];
    BX[r][c0+q+0]=v.x; BX[r][c0+q+1]=v.y; BX[r][c0+q+2]=v.z; BX[r][c0+q+3]=v.w;
  }
  __syncthreads();
  #pragma unroll
  for (int rr = 0; rr < 16; rr++) {
    const int idx = rr*256 + tid;
    const int i = idx >> 6, s = idx & 63;
    Ss[i][s] = Cs[i][s] * expf(csi[i]);
  }
  __syncthreads();
  #pragma unroll
  for (int k = 0; k < 64; k++) {
    float sv[4], xv[4];
    #pragma unroll
    for (int i = 0; i < 4; i++) sv[i] = Ss[ty*4+i][k];
    #pragma unroll
    for (int j = 0; j < 4; j++) xv[j] = BX[k][tx*4+j];
    #pragma unroll
    for (int i = 0; i < 4; i++)
      #pragma unroll
      for (int j = 0; j < 4; j++)
        acc[i][j] = fmaf(sv[i], xv[j], acc[i][j]);
  }
  // gate + store bf16
  #pragma unroll
  for (int i = 0; i < 4; i++) {
    const int pi = p_base + it*64 + ty*4 + i;
    #pragma unroll
    for (int j = 0; j < 4; j++) {
      const float rv = bf2f((u32)resb[(size_t)pi*64 + tx*4 + j]);
      yb[(size_t)pi*64 + tx*4 + j] = f2bf(acc[i][j] * siluf(rv));
    }
  }
}

extern "C" void kernel_launch(void* const* d_in, const int* in_sizes, int n_in,
                              void* d_out, int out_size, void* d_ws, size_t ws_size,
                              hipStream_t stream)
{
  const float* x       = (const float*)d_in[0];
  const float* w_in    = (const float*)d_in[1];
  const float* w_param = (const float*)d_in[2];
  const float* w_out   = (const float*)d_in[3];
  float* out = (float*)d_out;
  char* ws = (char*)d_ws;

  // layout (total 0xE400000 = 228 MiB), liveness-aliased:
  float* states    = (float*)(ws);                 // 16 MiB (aliases xb; written after xb dead)
  u16*   xb        = (u16*)  (ws);                 // 16 MiB
  u16*   yb        = (u16*)  (ws + 0x1000000ull);  // 32 MiB (aliases w_in_b; written after dead)
  u16*   w_in_b    = (u16*)  (ws + 0x1000000ull);  // 32 MiB
  u16*   w_param_b = (u16*)  (ws + 0x3000000ull);  // 8320*2048*2 = 33.2 MiB (64 pad rows)
  u16*   w_out_b   = (u16*)  (ws + 0x5100000ull);  // 16 MiB
  u16*   inp       = (u16*)  (ws + 0x6100000ull);  // 32 MiB
  u16*   resb      = (u16*)  (ws + 0x8100000ull);  // 32 MiB
  u16*   Bb        = (u16*)  (ws + 0xA100000ull);  // 32 MiB
  u16*   Cb        = (u16*)  (ws + 0xC100000ull);  // 32 MiB
  float* dtb       = (float*)(ws + 0xE100000ull);  // 1 MiB
  float* cs        = (float*)(ws + 0xE200000ull);  // 1 MiB
  float* achunk    = (float*)(ws + 0xE300000ull);  // 4 KiB

  cast_bf16<<<8192,  256, 0, stream>>>(x, xb);            // 8388608 el
  cast_bf16<<<16384, 256, 0, stream>>>(w_in, w_in_b);     // 16777216 el
  cast_bf16<<<16512, 256, 0, stream>>>(w_param, w_param_b); // 16908288 el
  cast_bf16<<<8192,  256, 0, stream>>>(w_out, w_out_b);   // 8388608 el

  gemm_in <<<dim3(64, 32), 256, 0, stream>>>(xb, w_in_b, inp, resb);
  gemm_par<<<dim3(65, 32), 256, 0, stream>>>(xb, w_param_b, dtb, Bb, Cb);
  ssd_phaseA<<<1024, 256, 0, stream>>>(dtb, Bb, inp, cs, achunk, states);
  ssd_scan<<<64, 256, 0, stream>>>(states, achunk);
  ssd_diag<<<dim3(4, 1024), 256, 0, stream>>>(Bb, Cb, inp, cs, states, resb, yb);
  gemm_out<<<dim3(16, 32), 256, 0, stream>>>(yb, w_out_b, out);
}

// Round 4
// 652.661 us; speedup vs baseline: 8.6938x; 1.7527x over previous
//
#include <hip/hip_runtime.h>
#include <math.h>

#define Q 256

typedef unsigned short u16;
typedef unsigned int u32;
typedef __attribute__((ext_vector_type(8))) short short8;
typedef __attribute__((ext_vector_type(4))) float f32x4;

__device__ __forceinline__ float bf2f(u32 u){
  union { float f; u32 i; } v; v.i = u << 16; return v.f;
}
__device__ __forceinline__ u16 f2bf(float f){
  union { float f; u32 i; } v; v.f = f;
  u32 r = (v.i + 0x7FFFu + ((v.i >> 16) & 1u)) >> 16;
  return (u16)r;
}
__device__ __forceinline__ float softplusf(float x){
  return x > 20.f ? x : log1pf(expf(x));
}
__device__ __forceinline__ float siluf(float x){
  return x / (1.f + expf(-x));
}

__device__ __forceinline__ void gload_lds16(const void* g, const void* l){
  __builtin_amdgcn_global_load_lds(
    (const __attribute__((address_space(1))) void*)(uintptr_t)g,
    (__attribute__((address_space(3))) void*)(u32)(uintptr_t)l,
    16, 0, 0);
}

// Swizzled byte offset into a [64][64] bf16 LDS tile (128-B rows):
// 16-B chunk index XOR'd with (row&7). col2 = byte offset within row.
__device__ __forceinline__ u32 swz_off(int row, int col2){
  return (u32)(row*128 + (col2 ^ ((row & 7) << 4)));
}
// MFMA fragment load: row-major swizzled tile, row + k-half kk, lk = lane>>4.
__device__ __forceinline__ short8 frag_ld(const u16* buf, int row, int kk, int lk){
  return *(const short8*)((const char*)buf + row*128 + (((kk*4 + lk) ^ (row & 7)) << 4));
}

__global__ __launch_bounds__(256) void cast_bf16(const float* __restrict__ in,
    u16* __restrict__ out)
{
  const size_t i = ((size_t)blockIdx.x * 256 + threadIdx.x) * 4;
  const float4 v = *(const float4*)(in + i);
  ushort4 o;
  o.x = f2bf(v.x); o.y = f2bf(v.y); o.z = f2bf(v.z); o.w = f2bf(v.w);
  *(ushort4*)(out + i) = o;
}

// MFMA GEMM core: C[128x128 tile] = A[M,K]bf16 @ B[N,K]bf16^T, fp32 acc.
#define MFMA_GEMM_CORE(Abf_, Bbf_, K_) \
  __shared__ short As[128*64]; \
  __shared__ short Bs[128*64]; \
  const int tid = threadIdx.x; \
  const int w = tid >> 6, l = tid & 63; \
  const int m0 = blockIdx.y * 128, n0 = blockIdx.x * 128; \
  const int wr = (w >> 1) * 64, wc = (w & 1) * 64; \
  const int sub = l >> 3; \
  const int scol = ((l & 7) ^ sub) * 8; \
  const int lr16 = l & 15; \
  const int koff = (l >> 4) << 4; \
  const int swz = (l & 7) << 4; \
  f32x4 acc[4][4]; \
  { f32x4 z = {0.f, 0.f, 0.f, 0.f}; \
    _Pragma("unroll") for (int m_ = 0; m_ < 4; m_++) \
    _Pragma("unroll") for (int n_ = 0; n_ < 4; n_++) acc[m_][n_] = z; } \
  const u16* Agp = (Abf_) + (size_t)m0 * (K_); \
  const u16* Bgp = (Bbf_) + (size_t)n0 * (K_); \
  for (int kt = 0; kt < (K_); kt += 64) { \
    __syncthreads(); \
    _Pragma("unroll") for (int i_ = 0; i_ < 4; i_++) { \
      const int rbase = i_*32 + w*8; \
      gload_lds16(Agp + (size_t)(rbase + sub)*(K_) + kt + scol, As + rbase*64); \
      gload_lds16(Bgp + (size_t)(rbase + sub)*(K_) + kt + scol, Bs + rbase*64); \
    } \
    __syncthreads(); \
    short8 af[2][4], bf[2][4]; \
    _Pragma("unroll") for (int kk = 0; kk < 2; kk++) { \
      _Pragma("unroll") for (int m_ = 0; m_ < 4; m_++) \
        af[kk][m_] = *(const short8*)((const char*)As + (wr + m_*16 + lr16)*128 + ((kk*64 + koff) ^ swz)); \
      _Pragma("unroll") for (int n_ = 0; n_ < 4; n_++) \
        bf[kk][n_] = *(const short8*)((const char*)Bs + (wc + n_*16 + lr16)*128 + ((kk*64 + koff) ^ swz)); \
    } \
    _Pragma("unroll") for (int m_ = 0; m_ < 4; m_++) \
    _Pragma("unroll") for (int n_ = 0; n_ < 4; n_++) \
    _Pragma("unroll") for (int kk = 0; kk < 2; kk++) \
      acc[m_][n_] = __builtin_amdgcn_mfma_f32_16x16x32_bf16(af[kk][m_], bf[kk][n_], acc[m_][n_], 0, 0, 0); \
  } \
  const int orow0 = m0 + wr + ((l >> 4) << 2); \
  const int ocol0 = n0 + wc + (l & 15);

__global__ __launch_bounds__(256) void gemm_in(const u16* __restrict__ A,
    const u16* __restrict__ B, u16* __restrict__ inp, u16* __restrict__ resb)
{
  MFMA_GEMM_CORE(A, B, 2048)
  #pragma unroll
  for (int m_ = 0; m_ < 4; m_++)
    #pragma unroll
    for (int n_ = 0; n_ < 4; n_++) {
      const int col = ocol0 + n_*16;
      #pragma unroll
      for (int j = 0; j < 4; j++) {
        const int row = orow0 + m_*16 + j;
        const u16 v = f2bf(acc[m_][n_][j]);
        if (col < 4096) inp[(size_t)row*4096 + col] = v;
        else            resb[(size_t)row*4096 + (col - 4096)] = v;
      }
    }
}

__global__ __launch_bounds__(256) void gemm_par(const u16* __restrict__ A,
    const u16* __restrict__ B, float* __restrict__ dtb,
    u16* __restrict__ Bb, u16* __restrict__ Cb)
{
  MFMA_GEMM_CORE(A, B, 2048)
  #pragma unroll
  for (int m_ = 0; m_ < 4; m_++)
    #pragma unroll
    for (int n_ = 0; n_ < 4; n_++) {
      const int col = ocol0 + n_*16;
      if (col < 8256) {
        const int h = col / 129, rr = col - h*129;
        #pragma unroll
        for (int j = 0; j < 4; j++) {
          const int row = orow0 + m_*16 + j;
          const float v = acc[m_][n_][j];
          if (rr == 0)      dtb[(size_t)row*64 + h] = v;
          else if (rr < 65) Bb[((size_t)row*64 + h)*64 + (rr-1)]  = f2bf(v);
          else              Cb[((size_t)row*64 + h)*64 + (rr-65)] = f2bf(v);
        }
      }
    }
}

__global__ __launch_bounds__(256) void gemm_out(const u16* __restrict__ A,
    const u16* __restrict__ B, float* __restrict__ C)
{
  MFMA_GEMM_CORE(A, B, 4096)
  #pragma unroll
  for (int m_ = 0; m_ < 4; m_++)
    #pragma unroll
    for (int n_ = 0; n_ < 4; n_++) {
      const int col = ocol0 + n_*16;
      #pragma unroll
      for (int j = 0; j < 4; j++)
        C[(size_t)(orow0 + m_*16 + j)*2048 + col] = acc[m_][n_][j];
    }
}

// Per chunk g: cumsum of log(a), A_chunk, and TRANSPOSED chunk state
// states_t[g][d][s] = sum_j exp(cs_last - cs_j) B[j][s] X[j][d]  (MFMA).
__global__ __launch_bounds__(256) void ssd_phaseA(const float* __restrict__ dtb,
    const u16* __restrict__ Bb, const u16* __restrict__ inp,
    float* __restrict__ cs_g, float* __restrict__ achunk, float* __restrict__ states_t)
{
  const int g = blockIdx.x, tid = threadIdx.x;
  const int p = g * Q + tid;
  __shared__ float sc[Q];
  __shared__ u16 sBt[64*64];   // [s][j] weighted, swizzled
  __shared__ u16 sXt[64*64];   // [d][j] swizzled
  sc[tid] = -softplusf(dtb[p]);
  __syncthreads();
  for (int off = 1; off < Q; off <<= 1) {
    float v = (tid >= off) ? sc[tid - off] : 0.f;
    __syncthreads();
    if (tid >= off) sc[tid] += v;
    __syncthreads();
  }
  cs_g[p] = sc[tid];
  const float cl = sc[Q-1];
  if (tid == 0) achunk[g] = expf(cl);

  const int w = tid >> 6, l = tid & 63;
  const int lrow = l & 15, lk = l >> 4;
  const int tj = tid & 63, tcb = (tid >> 6) * 16;
  f32x4 acc[4];
  { f32x4 z = {0,0,0,0}; acc[0]=z; acc[1]=z; acc[2]=z; acc[3]=z; }

  for (int js = 0; js < 4; js++) {
    __syncthreads();
    {
      const int jc = js*64 + tj;
      const float wj = expf(cl - sc[jc]);
      const size_t prow = ((size_t)g*Q + jc) * 64;
      union { uint4 v; u16 s[8]; } b0, b1, x0, x1;
      b0.v = *(const uint4*)&Bb[prow + tcb];
      b1.v = *(const uint4*)&Bb[prow + tcb + 8];
      x0.v = *(const uint4*)&inp[prow + tcb];
      x1.v = *(const uint4*)&inp[prow + tcb + 8];
      #pragma unroll
      for (int q = 0; q < 8; q++) {
        const int r0 = tcb + q, r1 = tcb + 8 + q;
        *(u16*)((char*)sBt + swz_off(r0, 2*tj)) = f2bf(wj * bf2f((u32)b0.s[q]));
        *(u16*)((char*)sBt + swz_off(r1, 2*tj)) = f2bf(wj * bf2f((u32)b1.s[q]));
        *(u16*)((char*)sXt + swz_off(r0, 2*tj)) = x0.s[q];
        *(u16*)((char*)sXt + swz_off(r1, 2*tj)) = x1.s[q];
      }
    }
    __syncthreads();
    short8 aX0 = frag_ld(sXt, w*16 + lrow, 0, lk);
    short8 aX1 = frag_ld(sXt, w*16 + lrow, 1, lk);
    #pragma unroll
    for (int n = 0; n < 4; n++) {
      short8 b0 = frag_ld(sBt, n*16 + lrow, 0, lk);
      short8 b1 = frag_ld(sBt, n*16 + lrow, 1, lk);
      acc[n] = __builtin_amdgcn_mfma_f32_16x16x32_bf16(aX0, b0, acc[n], 0, 0, 0);
      acc[n] = __builtin_amdgcn_mfma_f32_16x16x32_bf16(aX1, b1, acc[n], 0, 0, 0);
    }
  }
  #pragma unroll
  for (int reg = 0; reg < 4; reg++) {
    const int d = w*16 + lk*4 + reg;
    #pragma unroll
    for (int n = 0; n < 4; n++)
      states_t[(size_t)g*4096 + d*64 + n*16 + lrow] = acc[n][reg];
  }
}

// Sequential scan; in place, elementwise (layout-agnostic over [g][4096]).
__global__ __launch_bounds__(256) void ssd_scan(float* __restrict__ states,
    const float* __restrict__ achunk)
{
  const int n = blockIdx.x, tid = threadIdx.x;
  float S[16];
  #pragma unroll
  for (int k = 0; k < 16; k++) S[k] = 0.f;
  for (int c = 0; c < 16; c++) {
    const int g = n*16 + c;
    const float A = achunk[g];
    #pragma unroll
    for (int k = 0; k < 16; k++) {
      const size_t e = (size_t)g * 4096 + tid + k*256;
      const float st = states[e];
      states[e] = S[k];
      S[k] = fmaf(A, S[k], st);
    }
  }
}

// y_diag + y_inter + SiLU gate, all MFMA; writes bf16 yb.
__global__ __launch_bounds__(256) void ssd_diag(const u16* __restrict__ Bb,
    const u16* __restrict__ Cb, const u16* __restrict__ inp,
    const float* __restrict__ cs_g, const float* __restrict__ states_t,
    const u16* __restrict__ resb, u16* __restrict__ yb)
{
  const int g = blockIdx.y, it = blockIdx.x, tid = threadIdx.x;
  const int w = tid >> 6, l = tid & 63;
  const int lrow = l & 15, lk = l >> 4;
  const int p_base = g * Q;
  __shared__ u16 sC[64*64];   // [i][s] swz
  __shared__ u16 sB[64*64];   // [j][s] swz; reused as St [d][s] in inter
  __shared__ u16 sX[64*64];   // [d][j] swz (X transposed)
  __shared__ u16 sP[64*64];   // [i][j] swz (scores bf16)
  __shared__ float csi[64], csj[64];

  const int r = tid >> 2, c0 = (tid & 3) << 4;
  {
    const size_t prow = (size_t)(p_base + it*64 + r) * 64;
    uint4 v0 = *(const uint4*)&Cb[prow + c0];
    uint4 v1 = *(const uint4*)&Cb[prow + c0 + 8];
    *(uint4*)((char*)sC + swz_off(r, c0*2))      = v0;
    *(uint4*)((char*)sC + swz_off(r, c0*2 + 16)) = v1;
    if (tid < 64) csi[tid] = cs_g[p_base + it*64 + tid];
  }
  const int i0 = w * 16;
  const int xj = tid & 63, xdb = (tid >> 6) * 16;
  f32x4 accY[4];
  { f32x4 z = {0,0,0,0}; accY[0]=z; accY[1]=z; accY[2]=z; accY[3]=z; }

  for (int jt = 0; jt <= it; jt++) {
    __syncthreads();
    {
      const size_t prow = (size_t)(p_base + jt*64 + r) * 64;
      uint4 v0 = *(const uint4*)&Bb[prow + c0];
      uint4 v1 = *(const uint4*)&Bb[prow + c0 + 8];
      *(uint4*)((char*)sB + swz_off(r, c0*2))      = v0;
      *(uint4*)((char*)sB + swz_off(r, c0*2 + 16)) = v1;
      if (tid < 64) csj[tid] = cs_g[p_base + jt*64 + tid];
    }
    {
      // X transpose-stage: per instruction all 64 lanes write one LDS row
      // (d uniform per wave per q) -> conflict-free scalar ds_write_b16.
      const size_t prow = (size_t)(p_base + jt*64 + xj) * 64;
      union { uint4 v; u16 s[8]; } x0, x1;
      x0.v = *(const uint4*)&inp[prow + xdb];
      x1.v = *(const uint4*)&inp[prow + xdb + 8];
      #pragma unroll
      for (int q = 0; q < 8; q++) {
        *(u16*)((char*)sX + swz_off(xdb + q,     2*xj)) = x0.s[q];
        *(u16*)((char*)sX + swz_off(xdb + 8 + q, 2*xj)) = x1.s[q];
      }
    }
    __syncthreads();
    // scores: D[i][j] = C_i . B_j
    f32x4 sAcc[4];
    { f32x4 z = {0,0,0,0}; sAcc[0]=z; sAcc[1]=z; sAcc[2]=z; sAcc[3]=z; }
    {
      short8 aC0 = frag_ld(sC, i0 + lrow, 0, lk);
      short8 aC1 = frag_ld(sC, i0 + lrow, 1, lk);
      #pragma unroll
      for (int n = 0; n < 4; n++) {
        short8 b0 = frag_ld(sB, n*16 + lrow, 0, lk);
        short8 b1 = frag_ld(sB, n*16 + lrow, 1, lk);
        sAcc[n] = __builtin_amdgcn_mfma_f32_16x16x32_bf16(aC0, b0, sAcc[n], 0, 0, 0);
        sAcc[n] = __builtin_amdgcn_mfma_f32_16x16x32_bf16(aC1, b1, sAcc[n], 0, 0, 0);
      }
    }
    // mask + decay, write P (bf16) into own stripe of sP
    const bool full = (jt < it);
    #pragma unroll
    for (int n = 0; n < 4; n++) {
      const int j_l = n*16 + lrow;
      const float cj = csj[j_l];
      #pragma unroll
      for (int reg = 0; reg < 4; reg++) {
        const int i_l = i0 + lk*4 + reg;
        float s = 0.f;
        if (full || j_l <= i_l) s = sAcc[n][reg] * expf(csi[i_l] - cj);
        *(u16*)((char*)sP + swz_off(i_l, n*32 + 2*lrow)) = f2bf(s);
      }
    }
    // PV: y += P @ X  (A = own stripe of sP, B = sX rows d; same-wave DS order)
    {
      short8 aP0 = frag_ld(sP, i0 + lrow, 0, lk);
      short8 aP1 = frag_ld(sP, i0 + lrow, 1, lk);
      #pragma unroll
      for (int n = 0; n < 4; n++) {
        short8 x0f = frag_ld(sX, n*16 + lrow, 0, lk);
        short8 x1f = frag_ld(sX, n*16 + lrow, 1, lk);
        accY[n] = __builtin_amdgcn_mfma_f32_16x16x32_bf16(aP0, x0f, accY[n], 0, 0, 0);
        accY[n] = __builtin_amdgcn_mfma_f32_16x16x32_bf16(aP1, x1f, accY[n], 0, 0, 0);
      }
    }
  }
  // inter: y += exp(csi[i]) * (C @ S_prev), S_prev^T staged bf16 into sB
  __syncthreads();
  {
    const int d = tid & 63, sb = (tid >> 6) * 16;
    const float* srow = &states_t[(size_t)g*4096 + d*64 + sb];
    float4 f0 = *(const float4*)(srow);
    float4 f1 = *(const float4*)(srow + 4);
    float4 f2 = *(const float4*)(srow + 8);
    float4 f3 = *(const float4*)(srow + 12);
    union { uint4 v; u16 s[8]; } o0, o1;
    o0.s[0]=f2bf(f0.x); o0.s[1]=f2bf(f0.y); o0.s[2]=f2bf(f0.z); o0.s[3]=f2bf(f0.w);
    o0.s[4]=f2bf(f1.x); o0.s[5]=f2bf(f1.y); o0.s[6]=f2bf(f1.z); o0.s[7]=f2bf(f1.w);
    o1.s[0]=f2bf(f2.x); o1.s[1]=f2bf(f2.y); o1.s[2]=f2bf(f2.z); o1.s[3]=f2bf(f2.w);
    o1.s[4]=f2bf(f3.x); o1.s[5]=f2bf(f3.y); o1.s[6]=f2bf(f3.z); o1.s[7]=f2bf(f3.w);
    *(uint4*)((char*)sB + swz_off(d, sb*2))      = o0.v;
    *(uint4*)((char*)sB + swz_off(d, sb*2 + 16)) = o1.v;
  }
  __syncthreads();
  f32x4 accI[4];
  { f32x4 z = {0,0,0,0}; accI[0]=z; accI[1]=z; accI[2]=z; accI[3]=z; }
  {
    short8 aC0 = frag_ld(sC, i0 + lrow, 0, lk);
    short8 aC1 = frag_ld(sC, i0 + lrow, 1, lk);
    #pragma unroll
    for (int n = 0; n < 4; n++) {
      short8 s0 = frag_ld(sB, n*16 + lrow, 0, lk);
      short8 s1 = frag_ld(sB, n*16 + lrow, 1, lk);
      accI[n] = __builtin_amdgcn_mfma_f32_16x16x32_bf16(aC0, s0, accI[n], 0, 0, 0);
      accI[n] = __builtin_amdgcn_mfma_f32_16x16x32_bf16(aC1, s1, accI[n], 0, 0, 0);
    }
  }
  #pragma unroll
  for (int reg = 0; reg < 4; reg++) {
    const int i_l = i0 + lk*4 + reg;
    const float ei = expf(csi[i_l]);
    const size_t prow = (size_t)(p_base + it*64 + i_l) * 64;
    #pragma unroll
    for (int n = 0; n < 4; n++) {
      const int d = n*16 + lrow;
      const float yv = accY[n][reg] + ei * accI[n][reg];
      const float rv = bf2f((u32)resb[prow + d]);
      yb[prow + d] = f2bf(yv * siluf(rv));
    }
  }
}

extern "C" void kernel_launch(void* const* d_in, const int* in_sizes, int n_in,
                              void* d_out, int out_size, void* d_ws, size_t ws_size,
                              hipStream_t stream)
{
  const float* x       = (const float*)d_in[0];
  const float* w_in    = (const float*)d_in[1];
  const float* w_param = (const float*)d_in[2];
  const float* w_out   = (const float*)d_in[3];
  float* out = (float*)d_out;
  char* ws = (char*)d_ws;

  float* states    = (float*)(ws);                 // 16 MiB (aliases xb; xb dead by then)
  u16*   xb        = (u16*)  (ws);                 // 16 MiB
  u16*   yb        = (u16*)  (ws + 0x1000000ull);  // 32 MiB (aliases w_in_b)
  u16*   w_in_b    = (u16*)  (ws + 0x1000000ull);  // 32 MiB
  u16*   w_param_b = (u16*)  (ws + 0x3000000ull);  // 33.2 MiB (64 pad rows)
  u16*   w_out_b   = (u16*)  (ws + 0x5100000ull);  // 16 MiB
  u16*   inp       = (u16*)  (ws + 0x6100000ull);  // 32 MiB
  u16*   resb      = (u16*)  (ws + 0x8100000ull);  // 32 MiB
  u16*   Bb        = (u16*)  (ws + 0xA100000ull);  // 32 MiB
  u16*   Cb        = (u16*)  (ws + 0xC100000ull);  // 32 MiB
  float* dtb       = (float*)(ws + 0xE100000ull);  // 1 MiB
  float* cs        = (float*)(ws + 0xE200000ull);  // 1 MiB
  float* achunk    = (float*)(ws + 0xE300000ull);  // 4 KiB

  cast_bf16<<<8192,  256, 0, stream>>>(x, xb);
  cast_bf16<<<16384, 256, 0, stream>>>(w_in, w_in_b);
  cast_bf16<<<16512, 256, 0, stream>>>(w_param, w_param_b);
  cast_bf16<<<8192,  256, 0, stream>>>(w_out, w_out_b);

  gemm_in <<<dim3(64, 32), 256, 0, stream>>>(xb, w_in_b, inp, resb);
  gemm_par<<<dim3(65, 32), 256, 0, stream>>>(xb, w_param_b, dtb, Bb, Cb);
  ssd_phaseA<<<1024, 256, 0, stream>>>(dtb, Bb, inp, cs, achunk, states);
  ssd_scan<<<64, 256, 0, stream>>>(states, achunk);
  ssd_diag<<<dim3(4, 1024), 256, 0, stream>>>(Bb, Cb, inp, cs, states, resb, yb);
  gemm_out<<<dim3(16, 32), 256, 0, stream>>>(yb, w_out_b, out);
}

// Round 5
// 566.229 us; speedup vs baseline: 10.0209x; 1.1526x over previous
//
#include <hip/hip_runtime.h>
#include <math.h>

#define Q 256

typedef unsigned short u16;
typedef unsigned int u32;
typedef __attribute__((ext_vector_type(8))) short short8;
typedef __attribute__((ext_vector_type(4))) float f32x4;

__device__ __forceinline__ float bf2f(u32 u){
  union { float f; u32 i; } v; v.i = u << 16; return v.f;
}
__device__ __forceinline__ u16 f2bf(float f){
  union { float f; u32 i; } v; v.f = f;
  u32 r = (v.i + 0x7FFFu + ((v.i >> 16) & 1u)) >> 16;
  return (u16)r;
}
__device__ __forceinline__ float softplusf(float x){
  return x > 20.f ? x : log1pf(expf(x));
}
__device__ __forceinline__ float siluf(float x){
  return x / (1.f + expf(-x));
}

__device__ __forceinline__ void gload_lds16(const void* g, const void* l){
  __builtin_amdgcn_global_load_lds(
    (const __attribute__((address_space(1))) void*)(uintptr_t)g,
    (__attribute__((address_space(3))) void*)(u32)(uintptr_t)l,
    16, 0, 0);
}

__device__ __forceinline__ u32 swz_off(int row, int col2){
  return (u32)(row*128 + (col2 ^ ((row & 7) << 4)));
}
__device__ __forceinline__ short8 frag_ld(const u16* buf, int row, int kk, int lk){
  return *(const short8*)((const char*)buf + row*128 + (((kk*4 + lk) ^ (row & 7)) << 4));
}

__global__ __launch_bounds__(256) void cast_bf16(const float* __restrict__ in,
    u16* __restrict__ out)
{
  const size_t i = ((size_t)blockIdx.x * 256 + threadIdx.x) * 4;
  const float4 v = *(const float4*)(in + i);
  ushort4 o;
  o.x = f2bf(v.x); o.y = f2bf(v.y); o.z = f2bf(v.z); o.w = f2bf(v.w);
  *(ushort4*)(out + i) = o;
}

// ---------------- 256x256 pipelined MFMA core (ring-4 K-slice slots) -------
// 512 thr = 8 waves (2M x 4N); per wave 128x64 out = 8x4 frags; BK-slice = 32.
// Slot (32 KiB) = rows 0..255 x 128B; logical chunks 0-3 = A cols, 4-7 = B cols
// of one 32-wide K-slice, phys chunk = logical ^ (row&7). gload_lds linear dest,
// pre-swizzled per-lane global source. Phase: 12 ds_read_b128, stage next slot
// (4 gload_lds), 32 MFMA, vmcnt(8), s_barrier.
#define G256_VM8 asm volatile("s_waitcnt vmcnt(8)" ::: "memory")
#define G256_VM4 asm volatile("s_waitcnt vmcnt(4)" ::: "memory")
#define G256_VM0 asm volatile("s_waitcnt vmcnt(0)" ::: "memory")

#define G256_STAGE(s_) \
  _Pragma("unroll") for (int q = 0; q < 4; q++) \
    gload_lds16(sptr[q] + (s_)*32, lds + (((s_)&3)*32768) + (q*512 + tid)*16);

#define G256_PHASE(p_, dostage_, VMSTMT) { \
  const char* sb_ = lds + (((p_)&3)*32768); \
  short8 af_[8], bf_[4]; \
  _Pragma("unroll") for (int m = 0; m < 8; m++) af_[m] = *(const short8*)(sb_ + aoff[m]); \
  _Pragma("unroll") for (int n = 0; n < 4; n++) bf_[n] = *(const short8*)(sb_ + boff[n]); \
  if (dostage_) { G256_STAGE((p_)+3) } \
  __builtin_amdgcn_sched_barrier(0); \
  __builtin_amdgcn_s_setprio(1); \
  _Pragma("unroll") for (int m = 0; m < 8; m++) \
  _Pragma("unroll") for (int n = 0; n < 4; n++) \
    acc[m][n] = __builtin_amdgcn_mfma_f32_16x16x32_bf16(af_[m], bf_[n], acc[m][n], 0, 0, 0); \
  __builtin_amdgcn_s_setprio(0); \
  VMSTMT; \
  __builtin_amdgcn_s_barrier(); \
  __builtin_amdgcn_sched_barrier(0); \
}

// Defines m0,n0 from XCD-swizzled bid; runs full K pipeline; leaves acc + lane idx.
#define G256_CORE(A_, B_, K_, NTN_) \
  extern __shared__ char lds[]; \
  const int tid = threadIdx.x; \
  const int nwg = gridDim.x, bid = blockIdx.x; \
  const int wg = (bid & 7) * (nwg >> 3) + (bid >> 3); \
  const int m0 = (wg / (NTN_)) * 256, n0 = (wg % (NTN_)) * 256; \
  const int w = tid >> 6, l = tid & 63; \
  const int wr = w >> 2, wc = w & 3; \
  const int lr = l & 15, lk = l >> 4; \
  const u16* sptr[4]; \
  _Pragma("unroll") for (int q = 0; q < 4; q++) { \
    const int c = q*512 + tid; \
    const int r = c >> 3; \
    const int jl = (c & 7) ^ (r & 7); \
    sptr[q] = (jl < 4) ? ((A_) + (size_t)(m0 + r)*(K_) + jl*8) \
                       : ((B_) + (size_t)(n0 + r)*(K_) + (jl-4)*8); \
  } \
  int aoff[8], boff[4]; \
  _Pragma("unroll") for (int m = 0; m < 8; m++) { \
    const int r = wr*128 + m*16 + lr; \
    aoff[m] = r*128 + ((lk ^ (r & 7)) << 4); } \
  _Pragma("unroll") for (int n = 0; n < 4; n++) { \
    const int r = wc*64 + n*16 + lr; \
    boff[n] = r*128 + (((4 + lk) ^ (r & 7)) << 4); } \
  f32x4 acc[8][4]; \
  { f32x4 z = {0.f,0.f,0.f,0.f}; \
    _Pragma("unroll") for (int m = 0; m < 8; m++) \
    _Pragma("unroll") for (int n = 0; n < 4; n++) acc[m][n] = z; } \
  G256_STAGE(0) G256_STAGE(1) G256_STAGE(2) \
  G256_VM8; \
  __builtin_amdgcn_s_barrier(); \
  __builtin_amdgcn_sched_barrier(0); \
  { const int NPH = (K_)/32; \
    for (int p = 0; p < NPH-4; p += 2) { \
      G256_PHASE(p,   1, G256_VM8) \
      G256_PHASE(p+1, 1, G256_VM8) \
    } \
    G256_PHASE(NPH-4, 1, G256_VM8) \
    G256_PHASE(NPH-3, 0, G256_VM4) \
    G256_PHASE(NPH-2, 0, G256_VM0) \
    G256_PHASE(NPH-1, 0, (void)0) \
  }

__global__ void __launch_bounds__(512, 2) gemm_in256(const u16* __restrict__ A,
    const u16* __restrict__ B, u16* __restrict__ inp, u16* __restrict__ resb)
{
  G256_CORE(A, B, 2048, 32)
  #pragma unroll
  for (int m = 0; m < 8; m++)
    #pragma unroll
    for (int n = 0; n < 4; n++) {
      const int col = n0 + wc*64 + n*16 + lr;
      #pragma unroll
      for (int j = 0; j < 4; j++) {
        const int row = m0 + wr*128 + m*16 + lk*4 + j;
        const u16 v = f2bf(acc[m][n][j]);
        if (col < 4096) inp[(size_t)row*4096 + col] = v;
        else            resb[(size_t)row*4096 + (col - 4096)] = v;
      }
    }
}

__global__ void __launch_bounds__(512, 2) gemm_par256(const u16* __restrict__ A,
    const u16* __restrict__ B, float* __restrict__ dtb,
    u16* __restrict__ Bb, u16* __restrict__ Cb)
{
  G256_CORE(A, B, 2048, 33)
  #pragma unroll
  for (int m = 0; m < 8; m++)
    #pragma unroll
    for (int n = 0; n < 4; n++) {
      const int col = n0 + wc*64 + n*16 + lr;
      if (col < 8256) {
        const int h = col / 129, rr = col - h*129;
        #pragma unroll
        for (int j = 0; j < 4; j++) {
          const int row = m0 + wr*128 + m*16 + lk*4 + j;
          const float v = acc[m][n][j];
          if (rr == 0)      dtb[(size_t)row*64 + h] = v;
          else if (rr < 65) Bb[((size_t)row*64 + h)*64 + (rr-1)]  = f2bf(v);
          else              Cb[((size_t)row*64 + h)*64 + (rr-65)] = f2bf(v);
        }
      }
    }
}

// ---------------- old 128x128 core (kept for gemm_out) ----------------------
#define MFMA_GEMM_CORE(Abf_, Bbf_, K_) \
  __shared__ short As[128*64]; \
  __shared__ short Bs[128*64]; \
  const int tid = threadIdx.x; \
  const int w = tid >> 6, l = tid & 63; \
  const int m0 = blockIdx.y * 128, n0 = blockIdx.x * 128; \
  const int wr = (w >> 1) * 64, wc = (w & 1) * 64; \
  const int sub = l >> 3; \
  const int scol = ((l & 7) ^ sub) * 8; \
  const int lr16 = l & 15; \
  const int koff = (l >> 4) << 4; \
  const int swz = (l & 7) << 4; \
  f32x4 acc[4][4]; \
  { f32x4 z = {0.f, 0.f, 0.f, 0.f}; \
    _Pragma("unroll") for (int m_ = 0; m_ < 4; m_++) \
    _Pragma("unroll") for (int n_ = 0; n_ < 4; n_++) acc[m_][n_] = z; } \
  const u16* Agp = (Abf_) + (size_t)m0 * (K_); \
  const u16* Bgp = (Bbf_) + (size_t)n0 * (K_); \
  for (int kt = 0; kt < (K_); kt += 64) { \
    __syncthreads(); \
    _Pragma("unroll") for (int i_ = 0; i_ < 4; i_++) { \
      const int rbase = i_*32 + w*8; \
      gload_lds16(Agp + (size_t)(rbase + sub)*(K_) + kt + scol, As + rbase*64); \
      gload_lds16(Bgp + (size_t)(rbase + sub)*(K_) + kt + scol, Bs + rbase*64); \
    } \
    __syncthreads(); \
    short8 af[2][4], bf[2][4]; \
    _Pragma("unroll") for (int kk = 0; kk < 2; kk++) { \
      _Pragma("unroll") for (int m_ = 0; m_ < 4; m_++) \
        af[kk][m_] = *(const short8*)((const char*)As + (wr + m_*16 + lr16)*128 + ((kk*64 + koff) ^ swz)); \
      _Pragma("unroll") for (int n_ = 0; n_ < 4; n_++) \
        bf[kk][n_] = *(const short8*)((const char*)Bs + (wc + n_*16 + lr16)*128 + ((kk*64 + koff) ^ swz)); \
    } \
    _Pragma("unroll") for (int m_ = 0; m_ < 4; m_++) \
    _Pragma("unroll") for (int n_ = 0; n_ < 4; n_++) \
    _Pragma("unroll") for (int kk = 0; kk < 2; kk++) \
      acc[m_][n_] = __builtin_amdgcn_mfma_f32_16x16x32_bf16(af[kk][m_], bf[kk][n_], acc[m_][n_], 0, 0, 0); \
  } \
  const int orow0 = m0 + wr + ((l >> 4) << 2); \
  const int ocol0 = n0 + wc + (l & 15);

__global__ __launch_bounds__(256) void gemm_out(const u16* __restrict__ A,
    const u16* __restrict__ B, float* __restrict__ C)
{
  MFMA_GEMM_CORE(A, B, 4096)
  #pragma unroll
  for (int m_ = 0; m_ < 4; m_++)
    #pragma unroll
    for (int n_ = 0; n_ < 4; n_++) {
      const int col = ocol0 + n_*16;
      #pragma unroll
      for (int j = 0; j < 4; j++)
        C[(size_t)(orow0 + m_*16 + j)*2048 + col] = acc[m_][n_][j];
    }
}

// ---------------- SSD ------------------------------------------------------
__global__ __launch_bounds__(256) void ssd_phaseA(const float* __restrict__ dtb,
    const u16* __restrict__ Bb, const u16* __restrict__ inp,
    float* __restrict__ cs_g, float* __restrict__ achunk, float* __restrict__ states_t)
{
  const int g = blockIdx.x, tid = threadIdx.x;
  const int p = g * Q + tid;
  __shared__ float sc[Q];
  __shared__ u16 sBt[64*64];
  __shared__ u16 sXt[64*64];
  sc[tid] = -softplusf(dtb[p]);
  __syncthreads();
  for (int off = 1; off < Q; off <<= 1) {
    float v = (tid >= off) ? sc[tid - off] : 0.f;
    __syncthreads();
    if (tid >= off) sc[tid] += v;
    __syncthreads();
  }
  cs_g[p] = sc[tid];
  const float cl = sc[Q-1];
  if (tid == 0) achunk[g] = expf(cl);

  const int w = tid >> 6, l = tid & 63;
  const int lrow = l & 15, lk = l >> 4;
  const int tj = tid & 63, tcb = (tid >> 6) * 16;
  f32x4 acc[4];
  { f32x4 z = {0,0,0,0}; acc[0]=z; acc[1]=z; acc[2]=z; acc[3]=z; }

  for (int js = 0; js < 4; js++) {
    __syncthreads();
    {
      const int jc = js*64 + tj;
      const float wj = expf(cl - sc[jc]);
      const size_t prow = ((size_t)g*Q + jc) * 64;
      union { uint4 v; u16 s[8]; } b0, b1, x0, x1;
      b0.v = *(const uint4*)&Bb[prow + tcb];
      b1.v = *(const uint4*)&Bb[prow + tcb + 8];
      x0.v = *(const uint4*)&inp[prow + tcb];
      x1.v = *(const uint4*)&inp[prow + tcb + 8];
      #pragma unroll
      for (int q = 0; q < 8; q++) {
        const int r0 = tcb + q, r1 = tcb + 8 + q;
        *(u16*)((char*)sBt + swz_off(r0, 2*tj)) = f2bf(wj * bf2f((u32)b0.s[q]));
        *(u16*)((char*)sBt + swz_off(r1, 2*tj)) = f2bf(wj * bf2f((u32)b1.s[q]));
        *(u16*)((char*)sXt + swz_off(r0, 2*tj)) = x0.s[q];
        *(u16*)((char*)sXt + swz_off(r1, 2*tj)) = x1.s[q];
      }
    }
    __syncthreads();
    short8 aX0 = frag_ld(sXt, w*16 + lrow, 0, lk);
    short8 aX1 = frag_ld(sXt, w*16 + lrow, 1, lk);
    #pragma unroll
    for (int n = 0; n < 4; n++) {
      short8 b0 = frag_ld(sBt, n*16 + lrow, 0, lk);
      short8 b1 = frag_ld(sBt, n*16 + lrow, 1, lk);
      acc[n] = __builtin_amdgcn_mfma_f32_16x16x32_bf16(aX0, b0, acc[n], 0, 0, 0);
      acc[n] = __builtin_amdgcn_mfma_f32_16x16x32_bf16(aX1, b1, acc[n], 0, 0, 0);
    }
  }
  #pragma unroll
  for (int reg = 0; reg < 4; reg++) {
    const int d = w*16 + lk*4 + reg;
    #pragma unroll
    for (int n = 0; n < 4; n++)
      states_t[(size_t)g*4096 + d*64 + n*16 + lrow] = acc[n][reg];
  }
}

__global__ __launch_bounds__(256) void ssd_scan(float* __restrict__ states,
    const float* __restrict__ achunk)
{
  const int n = blockIdx.x, tid = threadIdx.x;
  float S[16];
  #pragma unroll
  for (int k = 0; k < 16; k++) S[k] = 0.f;
  for (int c = 0; c < 16; c++) {
    const int g = n*16 + c;
    const float A = achunk[g];
    #pragma unroll
    for (int k = 0; k < 16; k++) {
      const size_t e = (size_t)g * 4096 + tid + k*256;
      const float st = states[e];
      states[e] = S[k];
      S[k] = fmaf(A, S[k], st);
    }
  }
}

__global__ __launch_bounds__(256) void ssd_diag(const u16* __restrict__ Bb,
    const u16* __restrict__ Cb, const u16* __restrict__ inp,
    const float* __restrict__ cs_g, const float* __restrict__ states_t,
    const u16* __restrict__ resb, u16* __restrict__ yb)
{
  const int g = blockIdx.y, it = blockIdx.x, tid = threadIdx.x;
  const int w = tid >> 6, l = tid & 63;
  const int lrow = l & 15, lk = l >> 4;
  const int p_base = g * Q;
  __shared__ u16 sC[64*64];
  __shared__ u16 sB[64*64];
  __shared__ u16 sX[64*64];
  __shared__ u16 sP[64*64];
  __shared__ float csi[64], csj[64];

  const int r = tid >> 2, c0 = (tid & 3) << 4;
  {
    const size_t prow = (size_t)(p_base + it*64 + r) * 64;
    uint4 v0 = *(const uint4*)&Cb[prow + c0];
    uint4 v1 = *(const uint4*)&Cb[prow + c0 + 8];
    *(uint4*)((char*)sC + swz_off(r, c0*2))      = v0;
    *(uint4*)((char*)sC + swz_off(r, c0*2 + 16)) = v1;
    if (tid < 64) csi[tid] = cs_g[p_base + it*64 + tid];
  }
  const int i0 = w * 16;
  const int xj = tid & 63, xdb = (tid >> 6) * 16;
  f32x4 accY[4];
  { f32x4 z = {0,0,0,0}; accY[0]=z; accY[1]=z; accY[2]=z; accY[3]=z; }

  for (int jt = 0; jt <= it; jt++) {
    __syncthreads();
    {
      const size_t prow = (size_t)(p_base + jt*64 + r) * 64;
      uint4 v0 = *(const uint4*)&Bb[prow + c0];
      uint4 v1 = *(const uint4*)&Bb[prow + c0 + 8];
      *(uint4*)((char*)sB + swz_off(r, c0*2))      = v0;
      *(uint4*)((char*)sB + swz_off(r, c0*2 + 16)) = v1;
      if (tid < 64) csj[tid] = cs_g[p_base + jt*64 + tid];
    }
    {
      const size_t prow = (size_t)(p_base + jt*64 + xj) * 64;
      union { uint4 v; u16 s[8]; } x0, x1;
      x0.v = *(const uint4*)&inp[prow + xdb];
      x1.v = *(const uint4*)&inp[prow + xdb + 8];
      #pragma unroll
      for (int q = 0; q < 8; q++) {
        *(u16*)((char*)sX + swz_off(xdb + q,     2*xj)) = x0.s[q];
        *(u16*)((char*)sX + swz_off(xdb + 8 + q, 2*xj)) = x1.s[q];
      }
    }
    __syncthreads();
    f32x4 sAcc[4];
    { f32x4 z = {0,0,0,0}; sAcc[0]=z; sAcc[1]=z; sAcc[2]=z; sAcc[3]=z; }
    {
      short8 aC0 = frag_ld(sC, i0 + lrow, 0, lk);
      short8 aC1 = frag_ld(sC, i0 + lrow, 1, lk);
      #pragma unroll
      for (int n = 0; n < 4; n++) {
        short8 b0 = frag_ld(sB, n*16 + lrow, 0, lk);
        short8 b1 = frag_ld(sB, n*16 + lrow, 1, lk);
        sAcc[n] = __builtin_amdgcn_mfma_f32_16x16x32_bf16(aC0, b0, sAcc[n], 0, 0, 0);
        sAcc[n] = __builtin_amdgcn_mfma_f32_16x16x32_bf16(aC1, b1, sAcc[n], 0, 0, 0);
      }
    }
    const bool full = (jt < it);
    #pragma unroll
    for (int n = 0; n < 4; n++) {
      const int j_l = n*16 + lrow;
      const float cj = csj[j_l];
      #pragma unroll
      for (int reg = 0; reg < 4; reg++) {
        const int i_l = i0 + lk*4 + reg;
        float s = 0.f;
        if (full || j_l <= i_l) s = sAcc[n][reg] * expf(csi[i_l] - cj);
        *(u16*)((char*)sP + swz_off(i_l, n*32 + 2*lrow)) = f2bf(s);
      }
    }
    {
      short8 aP0 = frag_ld(sP, i0 + lrow, 0, lk);
      short8 aP1 = frag_ld(sP, i0 + lrow, 1, lk);
      #pragma unroll
      for (int n = 0; n < 4; n++) {
        short8 x0f = frag_ld(sX, n*16 + lrow, 0, lk);
        short8 x1f = frag_ld(sX, n*16 + lrow, 1, lk);
        accY[n] = __builtin_amdgcn_mfma_f32_16x16x32_bf16(aP0, x0f, accY[n], 0, 0, 0);
        accY[n] = __builtin_amdgcn_mfma_f32_16x16x32_bf16(aP1, x1f, accY[n], 0, 0, 0);
      }
    }
  }
  __syncthreads();
  {
    const int d = tid & 63, sb = (tid >> 6) * 16;
    const float* srow = &states_t[(size_t)g*4096 + d*64 + sb];
    float4 f0 = *(const float4*)(srow);
    float4 f1 = *(const float4*)(srow + 4);
    float4 f2 = *(const float4*)(srow + 8);
    float4 f3 = *(const float4*)(srow + 12);
    union { uint4 v; u16 s[8]; } o0, o1;
    o0.s[0]=f2bf(f0.x); o0.s[1]=f2bf(f0.y); o0.s[2]=f2bf(f0.z); o0.s[3]=f2bf(f0.w);
    o0.s[4]=f2bf(f1.x); o0.s[5]=f2bf(f1.y); o0.s[6]=f2bf(f1.z); o0.s[7]=f2bf(f1.w);
    o1.s[0]=f2bf(f2.x); o1.s[1]=f2bf(f2.y); o1.s[2]=f2bf(f2.z); o1.s[3]=f2bf(f2.w);
    o1.s[4]=f2bf(f3.x); o1.s[5]=f2bf(f3.y); o1.s[6]=f2bf(f3.z); o1.s[7]=f2bf(f3.w);
    *(uint4*)((char*)sB + swz_off(d, sb*2))      = o0.v;
    *(uint4*)((char*)sB + swz_off(d, sb*2 + 16)) = o1.v;
  }
  __syncthreads();
  f32x4 accI[4];
  { f32x4 z = {0,0,0,0}; accI[0]=z; accI[1]=z; accI[2]=z; accI[3]=z; }
  {
    short8 aC0 = frag_ld(sC, i0 + lrow, 0, lk);
    short8 aC1 = frag_ld(sC, i0 + lrow, 1, lk);
    #pragma unroll
    for (int n = 0; n < 4; n++) {
      short8 s0 = frag_ld(sB, n*16 + lrow, 0, lk);
      short8 s1 = frag_ld(sB, n*16 + lrow, 1, lk);
      accI[n] = __builtin_amdgcn_mfma_f32_16x16x32_bf16(aC0, s0, accI[n], 0, 0, 0);
      accI[n] = __builtin_amdgcn_mfma_f32_16x16x32_bf16(aC1, s1, accI[n], 0, 0, 0);
    }
  }
  #pragma unroll
  for (int reg = 0; reg < 4; reg++) {
    const int i_l = i0 + lk*4 + reg;
    const float ei = expf(csi[i_l]);
    const size_t prow = (size_t)(p_base + it*64 + i_l) * 64;
    #pragma unroll
    for (int n = 0; n < 4; n++) {
      const int d = n*16 + lrow;
      const float yv = accY[n][reg] + ei * accI[n][reg];
      const float rv = bf2f((u32)resb[prow + d]);
      yb[prow + d] = f2bf(yv * siluf(rv));
    }
  }
}

extern "C" void kernel_launch(void* const* d_in, const int* in_sizes, int n_in,
                              void* d_out, int out_size, void* d_ws, size_t ws_size,
                              hipStream_t stream)
{
  const float* x       = (const float*)d_in[0];
  const float* w_in    = (const float*)d_in[1];
  const float* w_param = (const float*)d_in[2];
  const float* w_out   = (const float*)d_in[3];
  float* out = (float*)d_out;
  char* ws = (char*)d_ws;

  float* states    = (float*)(ws);                 // 16 MiB (aliases xb)
  u16*   xb        = (u16*)  (ws);                 // 16 MiB
  u16*   yb        = (u16*)  (ws + 0x1000000ull);  // 32 MiB (aliases w_in_b)
  u16*   w_in_b    = (u16*)  (ws + 0x1000000ull);  // 32 MiB
  u16*   w_param_b = (u16*)  (ws + 0x3000000ull);  // 8448*2048*2 = 33 MiB (pad rows)
  u16*   w_out_b   = (u16*)  (ws + 0x5100000ull);  // 16 MiB
  u16*   inp       = (u16*)  (ws + 0x6100000ull);  // 32 MiB
  u16*   resb      = (u16*)  (ws + 0x8100000ull);  // 32 MiB
  u16*   Bb        = (u16*)  (ws + 0xA100000ull);  // 32 MiB
  u16*   Cb        = (u16*)  (ws + 0xC100000ull);  // 32 MiB
  float* dtb       = (float*)(ws + 0xE100000ull);  // 1 MiB
  float* cs        = (float*)(ws + 0xE200000ull);  // 1 MiB
  float* achunk    = (float*)(ws + 0xE300000ull);  // 4 KiB

  hipFuncSetAttribute((const void*)gemm_in256,
      hipFuncAttributeMaxDynamicSharedMemorySize, 131072);
  hipFuncSetAttribute((const void*)gemm_par256,
      hipFuncAttributeMaxDynamicSharedMemorySize, 131072);

  cast_bf16<<<8192,  256, 0, stream>>>(x, xb);
  cast_bf16<<<16384, 256, 0, stream>>>(w_in, w_in_b);
  cast_bf16<<<16512, 256, 0, stream>>>(w_param, w_param_b);
  cast_bf16<<<8192,  256, 0, stream>>>(w_out, w_out_b);

  gemm_in256 <<<512, 512, 131072, stream>>>(xb, w_in_b, inp, resb);
  gemm_par256<<<528, 512, 131072, stream>>>(xb, w_param_b, dtb, Bb, Cb);
  ssd_phaseA<<<1024, 256, 0, stream>>>(dtb, Bb, inp, cs, achunk, states);
  ssd_scan<<<64, 256, 0, stream>>>(states, achunk);
  ssd_diag<<<dim3(4, 1024), 256, 0, stream>>>(Bb, Cb, inp, cs, states, resb, yb);
  gemm_out<<<dim3(16, 32), 256, 0, stream>>>(yb, w_out_b, out);
}